// Round 3
// baseline (883.600 us; speedup 1.0000x reference)
//
#include <hip/hip_runtime.h>
#include <hip/hip_cooperative_groups.h>
#include <cstdint>
#include <cstddef>

#define BB 64
#define NN 8192
#define MM 128
#define NBLK 1024          // 16 blocks per batch, 4 blocks/CU (co-resident)
#define CPB 16             // chunks (blocks) per batch
#define RPB 512            // rows per block = NN / CPB

typedef float f4 __attribute__((ext_vector_type(4)));
namespace cg = cooperative_groups;

// Fully fused NTM addressing step, one cooperative kernel, 3 phases:
//  P1 score:  p[b,n] = exp(beta*cos(mem[b,n]+eps, k[b]+eps) - beta); per-block Sp.
//             (cos<=1 so the beta shift keeps exp in [e^-10,1] -- no max pass.)
//  P2 weight: wg = g*softmax + (1-g)*w_prev; circular 3-tap shift; t = wh^gamma
//             kept in LDS (never touches HBM); per-block Tp.
//  P3 update: w = t/(T+eps); r += w*mem; nmem = mem*(1-w*e) + w*a.
// Each block owns the SAME 512 rows in P1 and P3 -> P3's memory re-read is a
// deterministic L3 (partly L2) hit. NT stores for nmem (never re-read; don't
// evict the still-unread memory tail).
__global__ __launch_bounds__(256, 4) void fused_kernel(
        const float* __restrict__ memory, const float* __restrict__ k,
        const float* __restrict__ beta,   const float* __restrict__ g,
        const float* __restrict__ s,      const float* __restrict__ gamma,
        const float* __restrict__ w_prev, const float* __restrict__ e,
        const float* __restrict__ a,      float* __restrict__ r,
        float* __restrict__ nmem,         float* __restrict__ p,
        float* __restrict__ Sp,           float* __restrict__ Tp)
{
    __shared__ float wgs[RPB + 2];
    __shared__ float t_lds[RPB];
    __shared__ float red[4];
    __shared__ f4 sred[256];

    const int bi   = blockIdx.x;
    const int b    = bi >> 4;          // batch
    const int n0   = (bi & 15) * RPB;  // first row owned by this block
    const int tid  = threadIdx.x;
    const int lane = tid & 63;
    const int wid  = tid >> 6;         // wave 0..3
    const int l32  = lane & 31;
    const int half = lane >> 5;

    cg::grid_group grid = cg::this_grid();

    // ================= Phase 1: score =================
    {
        float4 kv = ((const float4*)(k + b * MM))[l32];
        kv.x += 1e-16f; kv.y += 1e-16f; kv.z += 1e-16f; kv.w += 1e-16f;
        float nk2 = kv.x * kv.x + kv.y * kv.y + kv.z * kv.z + kv.w * kv.w;
        #pragma unroll
        for (int o = 1; o < 32; o <<= 1) nk2 += __shfl_xor(nk2, o, 64);
        const float bv = beta[b];
        const float sb = bv / fmaxf(sqrtf(nk2), 1e-8f);

        const int row0 = n0 + wid * (RPB / 4);       // 128 rows per wave
        const float4* mp = (const float4*)(memory + ((size_t)b * NN + row0) * MM);
        float* pout = p + (size_t)b * NN + row0;

        float ls = 0.f;
        #pragma unroll 2
        for (int it = 0; it < RPB / 8; ++it) {       // 64 iters, 2 rows each
            float4 m = mp[it * 64 + lane];
            m.x += 1e-16f; m.y += 1e-16f; m.z += 1e-16f; m.w += 1e-16f;
            float pdot = m.x * kv.x + m.y * kv.y + m.z * kv.z + m.w * kv.w;
            float pnm  = m.x * m.x + m.y * m.y + m.z * m.z + m.w * m.w;
            #pragma unroll
            for (int o = 1; o < 32; o <<= 1) {
                pdot += __shfl_xor(pdot, o, 64);
                pnm  += __shfl_xor(pnm,  o, 64);
            }
            if (l32 == 0) {
                const float pe = __expf(sb * pdot / fmaxf(sqrtf(pnm), 1e-8f) - bv);
                pout[it * 2 + half] = pe;
                ls += pe;
            }
        }
        ls += __shfl_xor(ls, 32, 64);                // lane0 += lane32 partial
        if (lane == 0) red[wid] = ls;
    }
    __syncthreads();
    if (tid == 0) Sp[bi] = red[0] + red[1] + red[2] + red[3];
    __threadfence();
    grid.sync();

    // ================= Phase 2: weight (t stays in LDS) =================
    {
        float sv = (tid < CPB) ? Sp[(b << 4) + tid] : 0.f;
        #pragma unroll
        for (int o = 8; o > 0; o >>= 1) sv += __shfl_xor(sv, o, 64);
        if (tid == 0) red[0] = sv;
        __syncthreads();
        const float invS = 1.f / red[0];

        const float gv = g[b], omg = 1.f - gv;
        const float* pb = p + (size_t)b * NN;
        const float* wp = w_prev + (size_t)b * NN;
        #pragma unroll
        for (int j = 0; j < RPB / 256; j++) {
            const int i = tid + j * 256;
            wgs[1 + i] = gv * (pb[n0 + i] * invS) + omg * wp[n0 + i];
        }
        if (tid == 0) {
            const int im = (n0 - 1) & (NN - 1);      // circular halo left
            wgs[0] = gv * (pb[im] * invS) + omg * wp[im];
        } else if (tid == 1) {
            const int ip = (n0 + RPB) & (NN - 1);    // circular halo right
            wgs[RPB + 1] = gv * (pb[ip] * invS) + omg * wp[ip];
        }
        __syncthreads();

        const float s0 = s[b * 3 + 0], s1 = s[b * 3 + 1], s2 = s[b * 3 + 2];
        const float gam = gamma[b];
        float lsum = 0.f;
        #pragma unroll
        for (int j = 0; j < RPB / 256; j++) {
            const int i = tid + j * 256;
            const float wh = s0 * wgs[i] + s1 * wgs[i + 1] + s2 * wgs[i + 2];
            const float tv = __expf(gam * __logf(wh));   // wh > 0 guaranteed
            t_lds[i] = tv;
            lsum += tv;
        }
        #pragma unroll
        for (int o = 32; o > 0; o >>= 1) lsum += __shfl_xor(lsum, o, 64);
        __syncthreads();
        if ((tid & 63) == 0) red[tid >> 6] = lsum;
        __syncthreads();
        if (tid == 0) Tp[bi] = red[0] + red[1] + red[2] + red[3];
    }
    __threadfence();
    grid.sync();

    // ================= Phase 3: update (same rows as P1 -> cache-hot) =======
    {
        float tv = (tid < CPB) ? Tp[(b << 4) + tid] : 0.f;
        #pragma unroll
        for (int o = 8; o > 0; o >>= 1) tv += __shfl_xor(tv, o, 64);
        if (tid == 0) red[0] = tv;
        __syncthreads();
        const float invT = 1.f / (red[0] + 1e-16f);

        const int c4 = tid & 31;           // float4 column group
        const int rg = tid >> 5;           // row offset within group of 8
        const f4 e4 = ((const f4*)(e + b * MM))[c4];
        const f4 a4 = ((const f4*)(a + b * MM))[c4];
        const size_t base = ((size_t)b * NN + n0) * MM;
        const f4* min4 = (const f4*)(memory + base);
        f4* mout4      = (f4*)(nmem + base);

        f4 acc = {0.f, 0.f, 0.f, 0.f};
        #pragma unroll 4
        for (int it = 0; it < RPB; it += 8) {
            const int rr = it + rg;
            const float wv = t_lds[rr] * invT;
            const int idx = rr * 32 + c4;
            const f4 m4 = min4[idx];
            acc += wv * m4;
            f4 o4 = m4 * (1.f - wv * e4) + wv * a4;
            __builtin_nontemporal_store(o4, mout4 + idx);
        }

        sred[tid] = acc;
        __syncthreads();
        if (tid < 32) {
            f4 tt = sred[tid];
            #pragma unroll
            for (int j = 1; j < 8; j++) tt += sred[tid + j * 32];
            float* rp = r + b * MM + tid * 4;
            atomicAdd(rp + 0, tt.x);
            atomicAdd(rp + 1, tt.y);
            atomicAdd(rp + 2, tt.z);
            atomicAdd(rp + 3, tt.w);
        }
    }
}

extern "C" void kernel_launch(void* const* d_in, const int* in_sizes, int n_in,
                              void* d_out, int out_size, void* d_ws, size_t ws_size,
                              hipStream_t stream) {
    const float* memory = (const float*)d_in[0];
    const float* k      = (const float*)d_in[1];
    const float* beta   = (const float*)d_in[2];
    const float* g      = (const float*)d_in[3];
    const float* s      = (const float*)d_in[4];
    const float* gamma  = (const float*)d_in[5];
    const float* w_prev = (const float*)d_in[6];
    const float* e      = (const float*)d_in[7];
    const float* a      = (const float*)d_in[8];

    float* out  = (float*)d_out;
    float* r    = out;                       // [B, M]
    float* nmem = out + BB * MM;             // [B, N, M]

    float* p  = (float*)d_ws;                // [B, N] exp(logit - beta)
    float* Sp = p + (size_t)BB * NN;         // [NBLK] per-block softmax partials
    float* Tp = Sp + NBLK;                   // [NBLK] per-block sharpen partials

    hipMemsetAsync(r, 0, BB * MM * sizeof(float), stream);

    void* args[] = { (void*)&memory, (void*)&k, (void*)&beta, (void*)&g,
                     (void*)&s, (void*)&gamma, (void*)&w_prev, (void*)&e,
                     (void*)&a, (void*)&r, (void*)&nmem, (void*)&p,
                     (void*)&Sp, (void*)&Tp };
    hipLaunchCooperativeKernel((const void*)fused_kernel, dim3(NBLK), dim3(256),
                               args, 0, stream);
}

// Round 4
// 506.535 us; speedup vs baseline: 1.7444x; 1.7444x over previous
//
#include <hip/hip_runtime.h>
#include <cstdint>
#include <cstddef>

#define BB 64
#define NN 8192
#define MM 128
#define CHUNKS 32          // update: blocks per batch
#define BCH 4              // weight: chunks per batch
#define CELEM (NN / BCH)   // 2048 elements per weight block

typedef float f4 __attribute__((ext_vector_type(4)));

// ---------------- Kernel A: p[b,n] = exp(beta*cos(memory[b,n,:]+eps, k[b]+eps) - beta)
// 16 lanes per row: each lane owns 8 columns (two coalesced float4 loads), so the
// butterfly is 4 levels x 2 quantities per 4 rows (2 shfl/row vs 5/row before),
// and unroll-4 keeps 8 loads in flight. cos<=1 so the beta shift keeps exp() in
// [e^-10,1] -- no max pass. Per-wave partials to Sp (no atomics, no memset).
__global__ __launch_bounds__(256) void score_kernel(const float* __restrict__ memory,
                                                    const float* __restrict__ k,
                                                    const float* __restrict__ beta,
                                                    float* __restrict__ p,
                                                    float* __restrict__ Sp) {
    const int gw   = (blockIdx.x * 256 + threadIdx.x) >> 6;  // 0..8191
    const int lane = threadIdx.x & 63;
    const int b    = gw >> 7;          // 128 waves per batch
    const int ws   = gw & 127;
    const int gi   = lane >> 4;        // row-group 0..3 within an iteration
    const int l16  = lane & 15;        // lane within the 16-lane row group

    // k fragment: cols [l16*4 .. +3] and [64 + l16*4 .. +3]
    const f4* kp = (const f4*)(k + b * MM);
    f4 k0 = kp[l16]      + 1e-16f;
    f4 k1 = kp[16 + l16] + 1e-16f;
    float nk2 = k0.x*k0.x + k0.y*k0.y + k0.z*k0.z + k0.w*k0.w
              + k1.x*k1.x + k1.y*k1.y + k1.z*k1.z + k1.w*k1.w;
    #pragma unroll
    for (int o = 1; o < 16; o <<= 1) nk2 += __shfl_xor(nk2, o, 64);
    const float bv = beta[b];
    const float sb = bv / fmaxf(sqrtf(nk2), 1e-8f);

    const int row0 = ws * 64;                       // 64 rows per wave
    const float* mbase = memory + ((size_t)b * NN + row0) * MM;
    float* pout = p + (size_t)b * NN + row0;

    float ls = 0.f;
    #pragma unroll 4
    for (int it = 0; it < 16; ++it) {               // 4 rows per iteration
        const int rr = it * 4 + gi;
        const f4* mp = (const f4*)(mbase + (size_t)rr * MM);
        f4 m0 = mp[l16]      + 1e-16f;
        f4 m1 = mp[16 + l16] + 1e-16f;
        float pdot = m0.x*k0.x + m0.y*k0.y + m0.z*k0.z + m0.w*k0.w
                   + m1.x*k1.x + m1.y*k1.y + m1.z*k1.z + m1.w*k1.w;
        float pnm  = m0.x*m0.x + m0.y*m0.y + m0.z*m0.z + m0.w*m0.w
                   + m1.x*m1.x + m1.y*m1.y + m1.z*m1.z + m1.w*m1.w;
        #pragma unroll
        for (int o = 1; o < 16; o <<= 1) {
            pdot += __shfl_xor(pdot, o, 64);
            pnm  += __shfl_xor(pnm,  o, 64);
        }
        if (l16 == 0) {
            const float pe = __expf(sb * pdot / fmaxf(sqrtf(pnm), 1e-8f) - bv);
            pout[rr] = pe;                           // lanes 0,16,32,48: 4 contiguous
            ls += pe;
        }
    }
    ls += __shfl_xor(ls, 16, 64);                    // combine the 4 group partials
    ls += __shfl_xor(ls, 32, 64);
    if (lane == 0) Sp[(b << 7) + ws] = ls;
}

// ---------------- Kernel B: interpolation + circular shift + sharpen.
// Reduces Sp -> invS locally; per-block sharpen partial Tp (no atomics).
// cidx==0 blocks also zero r[b] (replaces the hipMemsetAsync dispatch).
__global__ __launch_bounds__(256) void weight_kernel(const float* __restrict__ p,
                                                     const float* __restrict__ Sp,
                                                     const float* __restrict__ g,
                                                     const float* __restrict__ s,
                                                     const float* __restrict__ gamma,
                                                     const float* __restrict__ w_prev,
                                                     float* __restrict__ t,
                                                     float* __restrict__ Tp,
                                                     float* __restrict__ r) {
    __shared__ float wgs[CELEM + 2];
    __shared__ float red[4];
    const int b    = blockIdx.x >> 2;
    const int cidx = blockIdx.x & 3;
    const int c0   = cidx * CELEM;
    const int tid  = threadIdx.x;

    if (cidx == 0 && tid < MM) r[b * MM + tid] = 0.f;

    // --- reduce the 128 per-wave softmax partials (redundantly per block) ---
    float sv = (tid < 128) ? Sp[(b << 7) + tid] : 0.f;
    #pragma unroll
    for (int o = 32; o > 0; o >>= 1) sv += __shfl_xor(sv, o, 64);
    if ((tid & 63) == 0) red[tid >> 6] = sv;
    __syncthreads();
    const float invS = 1.f / (red[0] + red[1]);

    const float gv = g[b], omg = 1.f - gv;
    const float* pb = p + (size_t)b * NN;
    const float* wp = w_prev + (size_t)b * NN;
    #pragma unroll
    for (int j = 0; j < CELEM / 256; j++) {
        const int i = tid + j * 256;
        wgs[1 + i] = gv * (pb[c0 + i] * invS) + omg * wp[c0 + i];
    }
    if (tid == 0) {
        const int im = (c0 - 1) & (NN - 1);          // circular halo left
        wgs[0] = gv * (pb[im] * invS) + omg * wp[im];
    } else if (tid == 1) {
        const int ip = (c0 + CELEM) & (NN - 1);      // circular halo right
        wgs[CELEM + 1] = gv * (pb[ip] * invS) + omg * wp[ip];
    }
    __syncthreads();

    const float s0 = s[b * 3 + 0], s1 = s[b * 3 + 1], s2 = s[b * 3 + 2];
    const float gam = gamma[b];
    float lsum = 0.f;
    float* tb = t + (size_t)b * NN + c0;
    #pragma unroll
    for (int j = 0; j < CELEM / 256; j++) {
        const int i = tid + j * 256;
        const float wh = s0 * wgs[i] + s1 * wgs[i + 1] + s2 * wgs[i + 2];
        const float tv = __expf(gam * __logf(wh));   // wh > 0 guaranteed
        tb[i] = tv;
        lsum += tv;
    }
    #pragma unroll
    for (int o = 32; o > 0; o >>= 1) lsum += __shfl_xor(lsum, o, 64);
    __syncthreads();                                  // red reuse
    if ((tid & 63) == 0) red[tid >> 6] = lsum;
    __syncthreads();
    if (tid == 0) Tp[b * 4 + cidx] = red[0] + red[1] + red[2] + red[3];
}

// ---------------- Kernel C: r[b,m] = sum_n w*mem ; new_mem = mem*(1 - w*e) + w*a
// w = t/(T+eps) folded in. REVERSE traversal (most-recently-scored rows first;
// memory == 256 MiB == exactly the Infinity Cache, round-3 proved the re-read
// can be ~100% L3 hits). PLAIN loads (must allocate/hit in L3); NT stores only
// (nmem never re-read; don't evict the still-unread memory tail).
__global__ __launch_bounds__(256) void update_kernel(const float* __restrict__ memory,
                                                     const float* __restrict__ t,
                                                     const float* __restrict__ Tp,
                                                     const float* __restrict__ e,
                                                     const float* __restrict__ a,
                                                     float* __restrict__ r,
                                                     float* __restrict__ nmem) {
    const int rev   = (BB * CHUNKS - 1) - (int)blockIdx.x;
    const int b     = rev / CHUNKS;
    const int chunk = rev % CHUNKS;
    const int rows  = NN / CHUNKS;          // 256
    const int n0    = chunk * rows;
    const int tid   = threadIdx.x;
    const int c4    = tid & 31;             // float4 column group
    const int rg    = tid >> 5;             // row offset within group of 8

    const f4 e4 = ((const f4*)(e + b * MM))[c4];
    const f4 a4 = ((const f4*)(a + b * MM))[c4];
    const float Tb = Tp[b * 4 + 0] + Tp[b * 4 + 1] + Tp[b * 4 + 2] + Tp[b * 4 + 3];
    const float invT = 1.f / (Tb + 1e-16f);
    const float* wb = t + (size_t)b * NN + n0;
    const size_t base = ((size_t)b * NN + n0) * MM;
    const f4* min4 = (const f4*)(memory + base);
    f4* mout4      = (f4*)(nmem + base);

    f4 acc = {0.f, 0.f, 0.f, 0.f};
    #pragma unroll 8
    for (int it = 0; it < rows; it += 8) {
        const int rr = it + rg;
        const float wv = wb[rr] * invT;
        const int idx = rr * 32 + c4;
        const f4 m4 = min4[idx];
        acc += wv * m4;
        f4 o4 = m4 * (1.f - wv * e4) + wv * a4;
        __builtin_nontemporal_store(o4, mout4 + idx);
    }

    __shared__ f4 sred[256];
    sred[tid] = acc;
    __syncthreads();
    if (tid < 32) {
        f4 tt = sred[tid];
        #pragma unroll
        for (int j = 1; j < 8; j++) tt += sred[tid + j * 32];
        float* rp = r + b * MM + tid * 4;
        atomicAdd(rp + 0, tt.x);
        atomicAdd(rp + 1, tt.y);
        atomicAdd(rp + 2, tt.z);
        atomicAdd(rp + 3, tt.w);
    }
}

extern "C" void kernel_launch(void* const* d_in, const int* in_sizes, int n_in,
                              void* d_out, int out_size, void* d_ws, size_t ws_size,
                              hipStream_t stream) {
    const float* memory = (const float*)d_in[0];
    const float* k      = (const float*)d_in[1];
    const float* beta   = (const float*)d_in[2];
    const float* g      = (const float*)d_in[3];
    const float* s      = (const float*)d_in[4];
    const float* gamma  = (const float*)d_in[5];
    const float* w_prev = (const float*)d_in[6];
    const float* e      = (const float*)d_in[7];
    const float* a      = (const float*)d_in[8];

    float* out  = (float*)d_out;
    float* r    = out;                       // [B, M]
    float* nmem = out + BB * MM;             // [B, N, M]

    float* p  = (float*)d_ws;                // [B, N] exp(logit - beta)
    float* t  = p + (size_t)BB * NN;         // [B, N] w_hat^gamma (unnormalized)
    float* Sp = t + (size_t)BB * NN;         // [B, 128] per-wave softmax partials
    float* Tp = Sp + (size_t)BB * 128;       // [B, 4]  per-block sharpen partials

    score_kernel<<<2048, 256, 0, stream>>>(memory, k, beta, p, Sp);
    weight_kernel<<<BB * BCH, 256, 0, stream>>>(p, Sp, g, s, gamma, w_prev, t, Tp, r);
    update_kernel<<<BB * CHUNKS, 256, 0, stream>>>(memory, t, Tp, e, a, r, nmem);
}